// Round 11
// baseline (831.368 us; speedup 1.0000x reference)
//
#include <hip/hip_runtime.h>
#include <cstdint>

#define D_MODEL 1024
#define RANK 128
#define K_RANK_ 128
#define N_KNOW 32768
#define COARSE_K 64
#define FINE_K 16
#define NTOK 4096
#define MSEL 96
#define DELTA 1.3e-3f
#define SC 8192

using u32 = unsigned int;
using u64 = unsigned long long;
typedef _Float16 half8 __attribute__((ext_vector_type(8)));
typedef __attribute__((ext_vector_type(4))) float f32x4;

__device__ __forceinline__ u32 ordf(float v) {
    u32 u = __float_as_uint(v);
    return (u & 0x80000000u) ? ~u : (u | 0x80000000u);
}
__device__ __forceinline__ float unordf(u32 o) {
    return (o & 0x80000000u) ? __uint_as_float(o ^ 0x80000000u)
                             : __uint_as_float(~o);
}
__device__ __forceinline__ ushort f2h(float f) {
    union { _Float16 h; ushort u; } cv; cv.h = (_Float16)f; return cv.u;
}
__device__ __forceinline__ float h2f(ushort u) {
    union { ushort u; _Float16 h; } cv; cv.u = u; return (float)cv.h;
}
__device__ __forceinline__ void gload16(const void* g, void* l) {
    __builtin_amdgcn_global_load_lds(
        (const __attribute__((address_space(1))) char*)g,
        (__attribute__((address_space(3))) char*)l, 16, 0, 0);
}

// ---------------------------------------------------------------------------
__global__ __launch_bounds__(256)
void kcvt_x(const float* __restrict__ in, ushort* __restrict__ xh)
{
    int i = blockIdx.x * 256 + threadIdx.x;
    float4 v = ((const float4*)in)[i];
    ((ushort4*)xh)[i] = make_ushort4(f2h(v.x), f2h(v.y), f2h(v.z), f2h(v.w));
}

// ---------------------------------------------------------------------------
__global__ __launch_bounds__(256)
void kcvt_wt(const float* __restrict__ W, ushort* __restrict__ out, int col0)
{
    __shared__ float tile[32][33];
    const int nb = blockIdx.x * 32;
    const int kb = blockIdx.y * 32;
    const int tx = threadIdx.x & 31, ty = threadIdx.x >> 5;
#pragma unroll
    for (int q = 0; q < 4; ++q)
        tile[ty + q * 8][tx] = W[(size_t)(kb + ty + q * 8) * N_KNOW + col0 + nb + tx];
    __syncthreads();
#pragma unroll
    for (int q = 0; q < 4; ++q) {
        float v = tile[tx][ty + q * 8];
        out[(size_t)(nb + ty + q * 8) * D_MODEL + kb + tx] = f2h(v);
    }
}

// ---------------------------------------------------------------------------
// K1f8: fp16 MFMA GEMM, 256x256 tile, BK=64, 512 threads (8 waves 2Mx4N).
// 8-phase counted-vmcnt schedule (r9-verified). fp16 logits out.
// SC=8192 -> 512 blocks/launch: 2 blocks/CU back-to-back, ramps overlap.
// ---------------------------------------------------------------------------
__global__ __launch_bounds__(512, 2)
void k1f8(const ushort* __restrict__ xh, const ushort* __restrict__ wt,
          ushort* __restrict__ L)
{
    __shared__ ushort lds[2][32768];   // [buf][A 256x64 | B 256x64] fp16

    const int tid = threadIdx.x;
    const int nwg = gridDim.x;                       // 512
    int wfl = blockIdx.x;
    wfl = (wfl & 7) * (nwg >> 3) + (wfl >> 3);       // XCD bijective swizzle
    const int bm = (wfl & 15) * 256;                 // 16 M-tiles
    const int bn = (wfl >> 4) * 256;                 // 32 N-tiles

    const int lane = tid & 63;
    const int wid = tid >> 6;
    const int wm = wid >> 2, wn = wid & 3;
    const int lr = lane & 15, g = lane >> 4;

    const ushort* gA[4]; const ushort* gB[4];
#pragma unroll
    for (int i = 0; i < 4; ++i) {
        const int o = i * 512 + tid;                 // 0..2047
        const int row = o >> 3;                      // 0..255
        const int gslot = (o & 7) ^ (row & 7);       // involution
        gA[i] = xh + (size_t)(bm + row) * D_MODEL + gslot * 8;
        gB[i] = wt + (size_t)(bn + row) * D_MODEL + gslot * 8;
    }

    int aoff[2][8], boff[2][4];
#pragma unroll
    for (int ks = 0; ks < 2; ++ks) {
#pragma unroll
        for (int mf = 0; mf < 8; ++mf) {
            int row = wm * 128 + mf * 16 + lr;
            aoff[ks][mf] = row * 128 + (((ks * 4 + g) ^ (row & 7)) << 4);
        }
#pragma unroll
        for (int nf = 0; nf < 4; ++nf) {
            int row = wn * 64 + nf * 16 + lr;
            boff[ks][nf] = 32768 + row * 128 + (((ks * 4 + g) ^ (row & 7)) << 4);
        }
    }

    f32x4 acc[8][4];
#pragma unroll
    for (int mf = 0; mf < 8; ++mf)
#pragma unroll
        for (int nf = 0; nf < 4; ++nf) acc[mf][nf] = (f32x4)(0.f);

#define SAH(b, t, h)                                                           \
    {                                                                          \
        gload16(gA[2*(h)]   + (t) * 64,                                        \
                (char*)&lds[(b)][0] + ((2*(h)) * 512 + tid) * 16);             \
        gload16(gA[2*(h)+1] + (t) * 64,                                        \
                (char*)&lds[(b)][0] + ((2*(h)+1) * 512 + tid) * 16);           \
    }
#define SBH(b, t, h)                                                           \
    {                                                                          \
        gload16(gB[2*(h)]   + (t) * 64,                                        \
                (char*)&lds[(b)][0] + 32768 + ((2*(h)) * 512 + tid) * 16);     \
        gload16(gB[2*(h)+1] + (t) * 64,                                        \
                (char*)&lds[(b)][0] + 32768 + ((2*(h)+1) * 512 + tid) * 16);   \
    }

#define LDA4(lb, ks, base)                                                     \
    a0 = *(const half8*)((lb) + aoff[ks][(base) + 0]);                         \
    a1 = *(const half8*)((lb) + aoff[ks][(base) + 1]);                         \
    a2 = *(const half8*)((lb) + aoff[ks][(base) + 2]);                         \
    a3 = *(const half8*)((lb) + aoff[ks][(base) + 3]);

#define LDB4(lb, ks, bb)                                                       \
    bb[0] = *(const half8*)((lb) + boff[ks][0]);                               \
    bb[1] = *(const half8*)((lb) + boff[ks][1]);                               \
    bb[2] = *(const half8*)((lb) + boff[ks][2]);                               \
    bb[3] = *(const half8*)((lb) + boff[ks][3]);

#define MFMA16(mbase, bb)                                                      \
    __builtin_amdgcn_s_setprio(1);                                             \
    _Pragma("unroll")                                                          \
    for (int nf = 0; nf < 4; ++nf) {                                           \
        acc[(mbase)+0][nf] = __builtin_amdgcn_mfma_f32_16x16x32_f16(           \
            a0, bb[nf], acc[(mbase)+0][nf], 0, 0, 0);                          \
        acc[(mbase)+1][nf] = __builtin_amdgcn_mfma_f32_16x16x32_f16(           \
            a1, bb[nf], acc[(mbase)+1][nf], 0, 0, 0);                          \
        acc[(mbase)+2][nf] = __builtin_amdgcn_mfma_f32_16x16x32_f16(           \
            a2, bb[nf], acc[(mbase)+2][nf], 0, 0, 0);                          \
        acc[(mbase)+3][nf] = __builtin_amdgcn_mfma_f32_16x16x32_f16(           \
            a3, bb[nf], acc[(mbase)+3][nf], 0, 0, 0);                          \
    }                                                                          \
    __builtin_amdgcn_s_setprio(0);

#define SBAR()                                                                 \
    __builtin_amdgcn_sched_barrier(0);                                         \
    __builtin_amdgcn_s_barrier();                                              \
    __builtin_amdgcn_sched_barrier(0);

    SBH(0, 0, 0); SBH(0, 0, 1);
    SAH(0, 0, 0); SAH(0, 0, 1);
    SBH(1, 1, 0); SBH(1, 1, 1);

    const char* lb0 = (const char*)&lds[0][0];
    const char* lb1 = (const char*)&lds[1][0];
    half8 b0q[4], b1q[4];

    for (int i = 0; i < 8; ++i) {
        const int t1 = 2 * i + 1;
        const int tn0 = 2 * i + 2, tn1 = 2 * i + 3;
        const bool st = tn0 < 16;
        half8 a0, a1, a2, a3;

        asm volatile("s_waitcnt vmcnt(4)" ::: "memory");
        SBAR();
        LDA4(lb0, 0, 0);
        LDB4(lb0, 0, b0q);
        SAH(1, t1, 0);
        MFMA16(0, b0q);
        LDA4(lb0, 1, 0);
        LDB4(lb0, 1, b1q);
        SAH(1, t1, 1);
        MFMA16(0, b1q);
        SBAR();
        LDA4(lb0, 0, 4);
        if (st) SBH(0, tn0, 0);
        MFMA16(4, b0q);
        LDA4(lb0, 1, 4);
        if (st) SBH(0, tn0, 1);
        MFMA16(4, b1q);
        if (i < 7) asm volatile("s_waitcnt vmcnt(4)" ::: "memory");
        else       asm volatile("s_waitcnt vmcnt(0)" ::: "memory");
        SBAR();
        LDA4(lb1, 0, 0);
        LDB4(lb1, 0, b0q);
        if (st) SAH(0, tn0, 0);
        MFMA16(0, b0q);
        LDA4(lb1, 1, 0);
        LDB4(lb1, 1, b1q);
        if (st) SAH(0, tn0, 1);
        MFMA16(0, b1q);
        SBAR();
        LDA4(lb1, 0, 4);
        if (st) SBH(1, tn1, 0);
        MFMA16(4, b0q);
        LDA4(lb1, 1, 4);
        if (st) SBH(1, tn1, 1);
        MFMA16(4, b1q);
    }
#undef SAH
#undef SBH
#undef LDA4
#undef LDB4
#undef MFMA16
#undef SBAR

    const int crow0 = bm + wm * 128 + g * 4;
    const int ccol  = bn + wn * 64 + lr;
#pragma unroll
    for (int mf = 0; mf < 8; ++mf)
#pragma unroll
        for (int nf = 0; nf < 4; ++nf)
#pragma unroll
            for (int r = 0; r < 4; ++r)
                L[(size_t)(crow0 + mf * 16 + r) * SC + ccol + nf * 16] =
                    f2h(acc[mf][nf][r]);
}

// ---------------------------------------------------------------------------
// K2: per-token running top-96 over an 8192-col stripe, two 4096-col halves.
// Stripe 0: bisection on half A seeds threshold, half B filtered against it.
// ---------------------------------------------------------------------------
template <int M>
__global__ __launch_bounds__(256)
void k2_topk(const ushort* __restrict__ L, u64* __restrict__ R,
             int col0, int stripe)
{
    const int tt = blockIdx.x;
    const int tid = threadIdx.x;

    __shared__ u64 buf[4224];
    __shared__ int scnt;
    __shared__ int sred[4];

    const uint4* row8 = (const uint4*)(L + (size_t)tt * SC);
    u64 key[16];

#define LOADKEYS(half)                                                         \
    _Pragma("unroll")                                                          \
    for (int q = 0; q < 2; ++q) {                                              \
        uint4 v = row8[(half) * 512 + q * 256 + tid];                          \
        const int c = col0 + (half) * 4096 + (q * 256 + tid) * 8;              \
        u32 wv[4] = {v.x, v.y, v.z, v.w};                                      \
        _Pragma("unroll")                                                      \
        for (int d = 0; d < 4; ++d) {                                          \
            float f0 = h2f((ushort)(wv[d] & 0xFFFFu));                         \
            float f1 = h2f((ushort)(wv[d] >> 16));                             \
            key[q * 8 + d * 2]     = ((u64)ordf(f0) << 32) | (u32)(N_KNOW - 1 - (c + d * 2)); \
            key[q * 8 + d * 2 + 1] = ((u64)ordf(f1) << 32) | (u32)(N_KNOW - 2 - (c + d * 2)); \
        }                                                                      \
    }

#define FILTERKEYS()                                                           \
    _Pragma("unroll")                                                          \
    for (int j = 0; j < 16; ++j)                                               \
        if (key[j] > tkey) {                                                   \
            int p = atomicAdd(&scnt, 1);                                       \
            if (p < 4224) buf[p] = key[j];                                     \
        }

    u64 tkey;
    if (stripe == 0) {
        LOADKEYS(0);
        u32 lo = 0, hi = 0xFFFFFFFFu;
        for (int it = 0; it < 28; ++it) {
            if (hi - lo <= 1) break;
            u32 mid = lo + ((hi - lo) >> 1);
            int c = 0;
#pragma unroll
            for (int j = 0; j < 16; ++j) c += ((u32)(key[j] >> 32) > mid) ? 1 : 0;
#pragma unroll
            for (int o = 32; o; o >>= 1) c += __shfl_xor(c, o);
            if ((tid & 63) == 0) sred[tid >> 6] = c;
            __syncthreads();
            c = sred[0] + sred[1] + sred[2] + sred[3];
            __syncthreads();
            if (c >= M) { lo = mid; if (c <= 768) break; }
            else hi = mid;
        }
        tkey = ((u64)lo << 32) | 0xFFFFFFFFull;
        if (tid == 0) scnt = 0;
        __syncthreads();
        FILTERKEYS();
        LOADKEYS(1);
        FILTERKEYS();
    } else {
        tkey = R[(size_t)tt * M + (M - 1)];
        if (tid < M) buf[tid] = R[(size_t)tt * M + tid];
        if (tid == 0) scnt = M;
        __syncthreads();
        LOADKEYS(0);
        FILTERKEYS();
        LOADKEYS(1);
        FILTERKEYS();
    }
    __syncthreads();
#undef LOADKEYS
#undef FILTERKEYS

    const int n = min(scnt, 4224);
    for (int i = tid; i < n; i += 256) {
        u64 ki = buf[i];
        int r = 0;
        for (int j = 0; j < n; ++j) r += (buf[j] > ki) ? 1 : 0;
        if (r < M) R[(size_t)tt * M + r] = ki;
    }
}

// ---------------------------------------------------------------------------
// K2b pipeline: band -> exec (parallel exact f32 re-score) -> final
// ---------------------------------------------------------------------------
__global__ __launch_bounds__(256)
void k2b_band(const u64* __restrict__ R96, u32* __restrict__ jobs,
              int* __restrict__ jobCount, u32* __restrict__ band)
{
    __shared__ float sv[4][MSEL];
    const int tid = threadIdx.x;
    const int w = tid >> 6, lane = tid & 63;
    const int tt = blockIdx.x * 4 + w;

    sv[w][lane] = unordf((u32)(R96[(size_t)tt * MSEL + lane] >> 32));
    if (lane < MSEL - 64)
        sv[w][lane + 64] = unordf((u32)(R96[(size_t)tt * MSEL + lane + 64] >> 32));
    __syncthreads();

    const float t = sv[w][COARSE_K - 1];
    int cg = 0, cl = 0;
    for (int j = lane; j < MSEL; j += 64) {
        cg += (sv[w][j] > t + DELTA) ? 1 : 0;
        cl += (sv[w][j] < t - DELTA) ? 1 : 0;
    }
#pragma unroll
    for (int o = 32; o; o >>= 1) { cg += __shfl_xor(cg, o); cl += __shfl_xor(cl, o); }

    int lo = cg, hi = MSEL - 1 - cl;
    if (lo > COARSE_K - 1) lo = COARSE_K - 1;
    if (hi < COARSE_K - 1) hi = COARSE_K - 1;

    u32 b;
    if (lo == COARSE_K - 1 && hi == COARSE_K - 1) {
        b = 0x80000000u | 63u | (63u << 8);
    } else {
        int nj = hi - lo + 1;
        int base = 0;
        if (lane == 0) base = atomicAdd(jobCount, nj);
        base = __shfl(base, 0);
        for (int k = lane; k < nj; k += 64)
            jobs[base + k] = ((u32)tt << 8) | (u32)(lo + k);
        b = (u32)lo | ((u32)hi << 8);
    }
    if (lane == 0) band[tt] = b;
}

__global__ __launch_bounds__(256)
void k2b_exec(const u32* __restrict__ jobs, const int* __restrict__ jobCount,
              const u64* __restrict__ R96, const float* __restrict__ x,
              const float* __restrict__ W, u64* __restrict__ nk)
{
    __shared__ float red[4];
    const int tid = threadIdx.x;
    const int n = *jobCount;
    for (int j = blockIdx.x; j < n; j += gridDim.x) {
        u32 jd = jobs[j];
        int tt = jd >> 8, idx = jd & 255;
        u64 key = R96[(size_t)tt * MSEL + idx];
        int col = (N_KNOW - 1) - (int)(u32)(key & 0xFFFFFFFFu);
        float p = 0.f;
#pragma unroll
        for (int q = 0; q < 4; ++q) {
            int k = tid + q * 256;
            p = fmaf(x[(size_t)tt * D_MODEL + k], W[(size_t)k * N_KNOW + col], p);
        }
#pragma unroll
        for (int o = 32; o; o >>= 1) p += __shfl_xor(p, o);
        if ((tid & 63) == 0) red[tid >> 6] = p;
        __syncthreads();
        if (tid == 0) {
            float e = red[0] + red[1] + red[2] + red[3];
            nk[(size_t)tt * MSEL + idx] = ((u64)ordf(e) << 32) | (key & 0xFFFFFFFFu);
        }
        __syncthreads();
    }
}

__global__ __launch_bounds__(128)
void k2b_final(const u64* __restrict__ R96, const u64* __restrict__ nk,
               const u32* __restrict__ band, u64* __restrict__ R64)
{
    const int tt = blockIdx.x;
    const int tid = threadIdx.x;
    __shared__ u64 keys[MSEL];
    __shared__ u64 nkk[MSEL];

    const u32 b = band[tt];
    if (tid < MSEL) keys[tid] = R96[(size_t)tt * MSEL + tid];
    const int lo = b & 0xFF, hi = (b >> 8) & 0xFF;
    const bool trivial = (b & 0x80000000u) != 0;
    if (!trivial && tid >= lo && tid <= hi && tid < MSEL)
        nkk[tid] = nk[(size_t)tt * MSEL + tid];
    __syncthreads();

    if (trivial) {
        if (tid < COARSE_K) R64[(size_t)tt * COARSE_K + tid] = keys[tid];
        return;
    }
    if (tid < lo) R64[(size_t)tt * COARSE_K + tid] = keys[tid];
    const int mwin = COARSE_K - lo;
    if (tid >= lo && tid <= hi) {
        u64 me = nkk[tid];
        int r = 0;
        for (int j = lo; j <= hi; ++j) r += (nkk[j] > me) ? 1 : 0;
        if (r < mwin) R64[(size_t)tt * COARSE_K + lo + r] = keys[tid];
    }
}

// ---------------------------------------------------------------------------
// K3f: front-end — one wave per token (4 tokens/block)
// ---------------------------------------------------------------------------
__device__ __forceinline__ void fma4(float4& a, float w, const float4& v) {
    a.x = fmaf(w, v.x, a.x); a.y = fmaf(w, v.y, a.y);
    a.z = fmaf(w, v.z, a.z); a.w = fmaf(w, v.w, a.w);
}

__global__ __launch_bounds__(256)
void k3f(const float* __restrict__ h, const float* __restrict__ Wq,
         const float* __restrict__ Kall, const u64* __restrict__ R,
         int* __restrict__ fidx, float* __restrict__ fw)
{
    __shared__ float hq[4][RANK];
    __shared__ float qv[4][K_RANK_];

    const int tid = threadIdx.x;
    const int w = tid >> 6, lane = tid & 63;
    const int tt = blockIdx.x * 4 + w;

    {
        float2 hv = *(const float2*)(h + (size_t)tt * RANK + lane * 2);
        hq[w][lane * 2] = hv.x;
        hq[w][lane * 2 + 1] = hv.y;
    }
    const u64 key = R[(size_t)tt * COARSE_K + lane];
    const int ci = (N_KNOW - 1) - (int)(u32)(key & 0xFFFFFFFFu);
    __syncthreads();

    {
        float s0 = 0.f, s1 = 0.f;
        const float4* w0 = (const float4*)(Wq + (size_t)(lane * 2) * RANK);
        const float4* w1 = (const float4*)(Wq + (size_t)(lane * 2 + 1) * RANK);
#pragma unroll
        for (int r4 = 0; r4 < RANK / 4; ++r4) {
            float4 a = w0[r4], b = w1[r4];
            const float* hh = &hq[w][r4 * 4];
            s0 = fmaf(a.x, hh[0], s0); s0 = fmaf(a.y, hh[1], s0);
            s0 = fmaf(a.z, hh[2], s0); s0 = fmaf(a.w, hh[3], s0);
            s1 = fmaf(b.x, hh[0], s1); s1 = fmaf(b.y, hh[1], s1);
            s1 = fmaf(b.z, hh[2], s1); s1 = fmaf(b.w, hh[3], s1);
        }
        qv[w][lane * 2] = s0;
        qv[w][lane * 2 + 1] = s1;
    }
    __syncthreads();

    float sc;
    {
        float s = 0.f;
        const float4* kr = (const float4*)(Kall + (size_t)ci * K_RANK_);
#pragma unroll
        for (int r4 = 0; r4 < K_RANK_ / 4; ++r4) {
            float4 a = kr[r4];
            const float* qq = &qv[w][r4 * 4];
            s = fmaf(a.x, qq[0], s); s = fmaf(a.y, qq[1], s);
            s = fmaf(a.z, qq[2], s); s = fmaf(a.w, qq[3], s);
        }
        sc = s * 0.08838834764831845f;   // 1/sqrt(128)
    }

    const u64 myk = ((u64)ordf(sc) << 32) | (u32)(63 - lane);
    int rnk = 0;
#pragma unroll
    for (int j = 0; j < 64; ++j) {
        u64 kj = __shfl(myk, j);
        rnk += (kj > myk) ? 1 : 0;
    }

    float smax = sc;
#pragma unroll
    for (int o = 32; o; o >>= 1) smax = fmaxf(smax, __shfl_xor(smax, o));
    float e = (rnk < FINE_K) ? expf(sc - smax) : 0.f;
    float esum = e;
#pragma unroll
    for (int o = 32; o; o >>= 1) esum += __shfl_xor(esum, o);
    if (rnk < FINE_K) {
        fidx[(size_t)tt * FINE_K + rnk] = ci;
        fw[(size_t)tt * FINE_K + rnk] = e / esum;
    }
}

// ---------------------------------------------------------------------------
// K3g: gather/combine — one token per block
// ---------------------------------------------------------------------------
__global__ __launch_bounds__(256)
void k3g(const int* __restrict__ fidx, const float* __restrict__ fw,
         const float* __restrict__ Vall, float* __restrict__ out)
{
    __shared__ int si[FINE_K];
    __shared__ float sw[FINE_K];
    const int tt = blockIdx.x;
    const int tid = threadIdx.x;
    if (tid < FINE_K) {
        si[tid] = fidx[(size_t)tt * FINE_K + tid];
        sw[tid] = fw[(size_t)tt * FINE_K + tid];
    }
    __syncthreads();

    float4 a = make_float4(0.f, 0.f, 0.f, 0.f);
#pragma unroll
    for (int f = 0; f < FINE_K; ++f) {
        const float4 v = *(const float4*)(Vall + (size_t)si[f] * D_MODEL + tid * 4);
        fma4(a, sw[f], v);
    }
    ((float4*)(out + (size_t)tt * D_MODEL))[tid] = a;
}

// ---------------------------------------------------------------------------
extern "C" void kernel_launch(void* const* d_in, const int* in_sizes, int n_in,
                              void* d_out, int out_size, void* d_ws, size_t ws_size,
                              hipStream_t stream)
{
    const float* x  = (const float*)d_in[0];
    const float* h  = (const float*)d_in[1];
    const float* Wr = (const float*)d_in[2];
    const float* Wq = (const float*)d_in[3];
    const float* Ka = (const float*)d_in[4];
    const float* Va = (const float*)d_in[5];
    float* out = (float*)d_out;

    const size_t fixed =
        (size_t)NTOK * D_MODEL * 2 +      // xh
        (size_t)NTOK * SC * 2 +           // L (fp16)
        (size_t)NTOK * MSEL * 8 * 2 +     // R96 + nk
        (size_t)NTOK * COARSE_K * 8 +     // R64
        (size_t)NTOK * MSEL * 4 +         // jobs
        4096 +                            // jobCount (padded)
        (size_t)NTOK * 4 +                // band
        (size_t)NTOK * FINE_K * 8;        // fidx + fw

    int WCH = N_KNOW;
    while (WCH > SC && fixed + (size_t)WCH * D_MODEL * 2 > ws_size)
        WCH >>= 1;

    char* p = (char*)d_ws;
    ushort* wt   = (ushort*)p;  p += (size_t)WCH * D_MODEL * 2;
    ushort* xh   = (ushort*)p;  p += (size_t)NTOK * D_MODEL * 2;
    ushort* Lh   = (ushort*)p;  p += (size_t)NTOK * SC * 2;
    u64*    R96  = (u64*)p;     p += (size_t)NTOK * MSEL * 8;
    u64*    nk   = (u64*)p;     p += (size_t)NTOK * MSEL * 8;
    u64*    R64  = (u64*)p;     p += (size_t)NTOK * COARSE_K * 8;
    u32*    jobs = (u32*)p;     p += (size_t)NTOK * MSEL * 4;
    int*    jobCount = (int*)p; p += 4096;
    u32*    band = (u32*)p;     p += (size_t)NTOK * 4;
    int*    fidx = (int*)p;     p += (size_t)NTOK * FINE_K * 4;
    float*  fw   = (float*)p;   p += (size_t)NTOK * FINE_K * 4;

    hipMemsetAsync(jobCount, 0, 4, stream);

    kcvt_x<<<NTOK * D_MODEL / 4 / 256, 256, 0, stream>>>(x, xh);

    const int nstripe = N_KNOW / SC;                 // 4
    const int spc = WCH / SC;
    for (int s = 0; s < nstripe; ++s) {
        if (s % spc == 0)
            kcvt_wt<<<dim3(WCH / 32, D_MODEL / 32), 256, 0, stream>>>(Wr, wt, s * SC);
        const ushort* wts = wt + (size_t)((s % spc) * SC) * D_MODEL;
        k1f8<<<(SC / 256) * (NTOK / 256), 512, 0, stream>>>(xh, wts, Lh);
        k2_topk<MSEL><<<NTOK, 256, 0, stream>>>(Lh, R96, s * SC, s);
    }

    k2b_band<<<NTOK / 4, 256, 0, stream>>>(R96, jobs, jobCount, band);
    k2b_exec<<<8192, 256, 0, stream>>>(jobs, jobCount, R96, x, Wr, nk);
    k2b_final<<<NTOK, 128, 0, stream>>>(R96, nk, band, R64);

    k3f<<<NTOK / 4, 256, 0, stream>>>(h, Wq, Ka, R64, fidx, fw);
    k3g<<<NTOK, 256, 0, stream>>>(fidx, fw, Va, out);
}

// Round 12
// 763.995 us; speedup vs baseline: 1.0882x; 1.0882x over previous
//
#include <hip/hip_runtime.h>
#include <cstdint>

#define D_MODEL 1024
#define RANK 128
#define K_RANK_ 128
#define N_KNOW 32768
#define COARSE_K 64
#define FINE_K 16
#define NTOK 4096
#define MSEL 96
#define DELTA 1.15e-3f
#define SC 4096
#define QSCALE 8192.0f
#define QINV (1.0f / 8192.0f)

using u32 = unsigned int;
using u64 = unsigned long long;
typedef _Float16 half8 __attribute__((ext_vector_type(8)));
typedef __attribute__((ext_vector_type(4))) float f32x4;

__device__ __forceinline__ u32 ordf(float v) {
    u32 u = __float_as_uint(v);
    return (u & 0x80000000u) ? ~u : (u | 0x80000000u);
}
__device__ __forceinline__ ushort f2h(float f) {
    union { _Float16 h; ushort u; } cv; cv.h = (_Float16)f; return cv.u;
}
__device__ __forceinline__ void gload16(const void* g, void* l) {
    __builtin_amdgcn_global_load_lds(
        (const __attribute__((address_space(1))) char*)g,
        (__attribute__((address_space(3))) char*)l, 16, 0, 0);
}

// ---------------------------------------------------------------------------
__global__ __launch_bounds__(256)
void kcvt_x(const float* __restrict__ in, ushort* __restrict__ xh)
{
    int i = blockIdx.x * 256 + threadIdx.x;
    float4 v = ((const float4*)in)[i];
    ((ushort4*)xh)[i] = make_ushort4(f2h(v.x), f2h(v.y), f2h(v.z), f2h(v.w));
}

// ---------------------------------------------------------------------------
__global__ __launch_bounds__(256)
void kcvt_wt(const float* __restrict__ W, ushort* __restrict__ out, int col0)
{
    __shared__ float tile[32][33];
    const int nb = blockIdx.x * 32;
    const int kb = blockIdx.y * 32;
    const int tx = threadIdx.x & 31, ty = threadIdx.x >> 5;
#pragma unroll
    for (int q = 0; q < 4; ++q)
        tile[ty + q * 8][tx] = W[(size_t)(kb + ty + q * 8) * N_KNOW + col0 + nb + tx];
    __syncthreads();
#pragma unroll
    for (int q = 0; q < 4; ++q) {
        float v = tile[tx][ty + q * 8];
        out[(size_t)(nb + ty + q * 8) * D_MODEL + kb + tx] = f2h(v);
    }
}

// ---------------------------------------------------------------------------
// K1f8: fp16 MFMA GEMM, 256x256 tile, BK=64, 512 threads (8 waves 2Mx4N).
// 8-phase counted-vmcnt schedule (r9-verified). Logits stored as u16
// FIXED-POINT: q = rint(s*8192)+32768 (clamped). Uniform quant err 6.1e-5;
// clamp only affects scores > 4.0 which are guaranteed top-64 members.
// ---------------------------------------------------------------------------
__global__ __launch_bounds__(512, 2)
void k1f8(const ushort* __restrict__ xh, const ushort* __restrict__ wt,
          ushort* __restrict__ L)
{
    __shared__ ushort lds[2][32768];   // [buf][A 256x64 | B 256x64] fp16

    const int tid = threadIdx.x;
    const int nwg = gridDim.x;                       // 256
    int wfl = blockIdx.x;
    wfl = (wfl & 7) * (nwg >> 3) + (wfl >> 3);       // XCD bijective swizzle
    const int bm = (wfl & 15) * 256;
    const int bn = (wfl >> 4) * 256;

    const int lane = tid & 63;
    const int wid = tid >> 6;
    const int wm = wid >> 2, wn = wid & 3;
    const int lr = lane & 15, g = lane >> 4;

    const ushort* gA[4]; const ushort* gB[4];
#pragma unroll
    for (int i = 0; i < 4; ++i) {
        const int o = i * 512 + tid;                 // 0..2047
        const int row = o >> 3;                      // 0..255
        const int gslot = (o & 7) ^ (row & 7);       // involution
        gA[i] = xh + (size_t)(bm + row) * D_MODEL + gslot * 8;
        gB[i] = wt + (size_t)(bn + row) * D_MODEL + gslot * 8;
    }

    int aoff[2][8], boff[2][4];
#pragma unroll
    for (int ks = 0; ks < 2; ++ks) {
#pragma unroll
        for (int mf = 0; mf < 8; ++mf) {
            int row = wm * 128 + mf * 16 + lr;
            aoff[ks][mf] = row * 128 + (((ks * 4 + g) ^ (row & 7)) << 4);
        }
#pragma unroll
        for (int nf = 0; nf < 4; ++nf) {
            int row = wn * 64 + nf * 16 + lr;
            boff[ks][nf] = 32768 + row * 128 + (((ks * 4 + g) ^ (row & 7)) << 4);
        }
    }

    f32x4 acc[8][4];
#pragma unroll
    for (int mf = 0; mf < 8; ++mf)
#pragma unroll
        for (int nf = 0; nf < 4; ++nf) acc[mf][nf] = (f32x4)(0.f);

#define SAH(b, t, h)                                                           \
    {                                                                          \
        gload16(gA[2*(h)]   + (t) * 64,                                        \
                (char*)&lds[(b)][0] + ((2*(h)) * 512 + tid) * 16);             \
        gload16(gA[2*(h)+1] + (t) * 64,                                        \
                (char*)&lds[(b)][0] + ((2*(h)+1) * 512 + tid) * 16);           \
    }
#define SBH(b, t, h)                                                           \
    {                                                                          \
        gload16(gB[2*(h)]   + (t) * 64,                                        \
                (char*)&lds[(b)][0] + 32768 + ((2*(h)) * 512 + tid) * 16);     \
        gload16(gB[2*(h)+1] + (t) * 64,                                        \
                (char*)&lds[(b)][0] + 32768 + ((2*(h)+1) * 512 + tid) * 16);   \
    }

#define LDA4(lb, ks, base)                                                     \
    a0 = *(const half8*)((lb) + aoff[ks][(base) + 0]);                         \
    a1 = *(const half8*)((lb) + aoff[ks][(base) + 1]);                         \
    a2 = *(const half8*)((lb) + aoff[ks][(base) + 2]);                         \
    a3 = *(const half8*)((lb) + aoff[ks][(base) + 3]);

#define LDB4(lb, ks, bb)                                                       \
    bb[0] = *(const half8*)((lb) + boff[ks][0]);                               \
    bb[1] = *(const half8*)((lb) + boff[ks][1]);                               \
    bb[2] = *(const half8*)((lb) + boff[ks][2]);                               \
    bb[3] = *(const half8*)((lb) + boff[ks][3]);

#define MFMA16(mbase, bb)                                                      \
    __builtin_amdgcn_s_setprio(1);                                             \
    _Pragma("unroll")                                                          \
    for (int nf = 0; nf < 4; ++nf) {                                           \
        acc[(mbase)+0][nf] = __builtin_amdgcn_mfma_f32_16x16x32_f16(           \
            a0, bb[nf], acc[(mbase)+0][nf], 0, 0, 0);                          \
        acc[(mbase)+1][nf] = __builtin_amdgcn_mfma_f32_16x16x32_f16(           \
            a1, bb[nf], acc[(mbase)+1][nf], 0, 0, 0);                          \
        acc[(mbase)+2][nf] = __builtin_amdgcn_mfma_f32_16x16x32_f16(           \
            a2, bb[nf], acc[(mbase)+2][nf], 0, 0, 0);                          \
        acc[(mbase)+3][nf] = __builtin_amdgcn_mfma_f32_16x16x32_f16(           \
            a3, bb[nf], acc[(mbase)+3][nf], 0, 0, 0);                          \
    }                                                                          \
    __builtin_amdgcn_s_setprio(0);

#define SBAR()                                                                 \
    __builtin_amdgcn_sched_barrier(0);                                         \
    __builtin_amdgcn_s_barrier();                                              \
    __builtin_amdgcn_sched_barrier(0);

    SBH(0, 0, 0); SBH(0, 0, 1);
    SAH(0, 0, 0); SAH(0, 0, 1);
    SBH(1, 1, 0); SBH(1, 1, 1);

    const char* lb0 = (const char*)&lds[0][0];
    const char* lb1 = (const char*)&lds[1][0];
    half8 b0q[4], b1q[4];

    for (int i = 0; i < 8; ++i) {
        const int t1 = 2 * i + 1;
        const int tn0 = 2 * i + 2, tn1 = 2 * i + 3;
        const bool st = tn0 < 16;
        half8 a0, a1, a2, a3;

        asm volatile("s_waitcnt vmcnt(4)" ::: "memory");
        SBAR();
        LDA4(lb0, 0, 0);
        LDB4(lb0, 0, b0q);
        SAH(1, t1, 0);
        MFMA16(0, b0q);
        LDA4(lb0, 1, 0);
        LDB4(lb0, 1, b1q);
        SAH(1, t1, 1);
        MFMA16(0, b1q);
        SBAR();
        LDA4(lb0, 0, 4);
        if (st) SBH(0, tn0, 0);
        MFMA16(4, b0q);
        LDA4(lb0, 1, 4);
        if (st) SBH(0, tn0, 1);
        MFMA16(4, b1q);
        if (i < 7) asm volatile("s_waitcnt vmcnt(4)" ::: "memory");
        else       asm volatile("s_waitcnt vmcnt(0)" ::: "memory");
        SBAR();
        LDA4(lb1, 0, 0);
        LDB4(lb1, 0, b0q);
        if (st) SAH(0, tn0, 0);
        MFMA16(0, b0q);
        LDA4(lb1, 1, 0);
        LDB4(lb1, 1, b1q);
        if (st) SAH(0, tn0, 1);
        MFMA16(0, b1q);
        SBAR();
        LDA4(lb1, 0, 4);
        if (st) SBH(1, tn1, 0);
        MFMA16(4, b0q);
        LDA4(lb1, 1, 4);
        if (st) SBH(1, tn1, 1);
        MFMA16(4, b1q);
    }
#undef SAH
#undef SBH
#undef LDA4
#undef LDB4
#undef MFMA16
#undef SBAR

    const int crow0 = bm + wm * 128 + g * 4;
    const int ccol  = bn + wn * 64 + lr;
#pragma unroll
    for (int mf = 0; mf < 8; ++mf)
#pragma unroll
        for (int nf = 0; nf < 4; ++nf)
#pragma unroll
            for (int r = 0; r < 4; ++r) {
                int q = __float2int_rn(acc[mf][nf][r] * QSCALE) + 32768;
                q = q < 0 ? 0 : (q > 65535 ? 65535 : q);
                L[(size_t)(crow0 + mf * 16 + r) * SC + ccol + nf * 16] = (ushort)q;
            }
}

// ---------------------------------------------------------------------------
// K2: per-token running top-96 merge per stripe. u16 fixed-point keys —
// pure integer construction (2 ops/elem), 17-iter bisection on 16-bit space.
// ---------------------------------------------------------------------------
template <int M>
__global__ __launch_bounds__(256)
void k2_topk(const ushort* __restrict__ L, u64* __restrict__ R,
             int col0, int stripe)
{
    const int tt = blockIdx.x;
    const int tid = threadIdx.x;

    __shared__ u64 buf[4224];
    __shared__ int scnt;
    __shared__ int sred[4];

    u64 key[16];
    const uint4* row8 = (const uint4*)(L + (size_t)tt * SC);
#pragma unroll
    for (int q = 0; q < 2; ++q) {
        uint4 v = row8[q * 256 + tid];
        const int c = col0 + (q * 256 + tid) * 8;
        u32 wv[4] = {v.x, v.y, v.z, v.w};
#pragma unroll
        for (int d = 0; d < 4; ++d) {
            key[q * 8 + d * 2]     = ((u64)(wv[d] & 0xFFFFu) << 32) | (u32)(N_KNOW - 1 - (c + d * 2));
            key[q * 8 + d * 2 + 1] = ((u64)(wv[d] >> 16) << 32)    | (u32)(N_KNOW - 2 - (c + d * 2));
        }
    }

    u64 tkey;
    if (stripe == 0) {
        u32 lo = 0, hi = 65536;
        for (int it = 0; it < 17; ++it) {
            if (hi - lo <= 1) break;
            u32 mid = lo + ((hi - lo) >> 1);
            int c = 0;
#pragma unroll
            for (int j = 0; j < 16; ++j) c += ((u32)(key[j] >> 32) > mid) ? 1 : 0;
#pragma unroll
            for (int o = 32; o; o >>= 1) c += __shfl_xor(c, o);
            if ((tid & 63) == 0) sred[tid >> 6] = c;
            __syncthreads();
            c = sred[0] + sred[1] + sred[2] + sred[3];
            __syncthreads();
            if (c >= M) { lo = mid; if (c <= 768) break; }
            else hi = mid;
        }
        tkey = ((u64)lo << 32) | 0xFFFFFFFFull;
        if (tid == 0) scnt = 0;
    } else {
        tkey = R[(size_t)tt * M + (M - 1)];
        if (tid < M) buf[tid] = R[(size_t)tt * M + tid];
        if (tid == 0) scnt = M;
    }
    __syncthreads();

#pragma unroll
    for (int j = 0; j < 16; ++j)
        if (key[j] > tkey) {
            int p = atomicAdd(&scnt, 1);
            if (p < 4224) buf[p] = key[j];
        }
    __syncthreads();

    const int n = min(scnt, 4224);
    for (int i = tid; i < n; i += 256) {
        u64 ki = buf[i];
        int r = 0;
        for (int j = 0; j < n; ++j) r += (buf[j] > ki) ? 1 : 0;
        if (r < M) R[(size_t)tt * M + r] = ki;
    }
}

// ---------------------------------------------------------------------------
// K2b pipeline: band -> exec (parallel exact f32 re-score) -> final
// ---------------------------------------------------------------------------
__global__ __launch_bounds__(256)
void k2b_band(const u64* __restrict__ R96, u32* __restrict__ jobs,
              int* __restrict__ jobCount, u32* __restrict__ band)
{
    __shared__ float sv[4][MSEL];
    const int tid = threadIdx.x;
    const int w = tid >> 6, lane = tid & 63;
    const int tt = blockIdx.x * 4 + w;

    sv[w][lane] = ((int)(u32)(R96[(size_t)tt * MSEL + lane] >> 32) - 32768) * QINV;
    if (lane < MSEL - 64)
        sv[w][lane + 64] = ((int)(u32)(R96[(size_t)tt * MSEL + lane + 64] >> 32) - 32768) * QINV;
    __syncthreads();

    const float t = sv[w][COARSE_K - 1];
    int cg = 0, cl = 0;
    for (int j = lane; j < MSEL; j += 64) {
        cg += (sv[w][j] > t + DELTA) ? 1 : 0;
        cl += (sv[w][j] < t - DELTA) ? 1 : 0;
    }
#pragma unroll
    for (int o = 32; o; o >>= 1) { cg += __shfl_xor(cg, o); cl += __shfl_xor(cl, o); }

    int lo = cg, hi = MSEL - 1 - cl;
    if (lo > COARSE_K - 1) lo = COARSE_K - 1;
    if (hi < COARSE_K - 1) hi = COARSE_K - 1;

    u32 b;
    if (lo == COARSE_K - 1 && hi == COARSE_K - 1) {
        b = 0x80000000u | 63u | (63u << 8);
    } else {
        int nj = hi - lo + 1;
        int base = 0;
        if (lane == 0) base = atomicAdd(jobCount, nj);
        base = __shfl(base, 0);
        for (int k = lane; k < nj; k += 64)
            jobs[base + k] = ((u32)tt << 8) | (u32)(lo + k);
        b = (u32)lo | ((u32)hi << 8);
    }
    if (lane == 0) band[tt] = b;
}

__global__ __launch_bounds__(256)
void k2b_exec(const u32* __restrict__ jobs, const int* __restrict__ jobCount,
              const u64* __restrict__ R96, const float* __restrict__ x,
              const float* __restrict__ W, u64* __restrict__ nk)
{
    __shared__ float red[4];
    const int tid = threadIdx.x;
    const int n = *jobCount;
    for (int j = blockIdx.x; j < n; j += gridDim.x) {
        u32 jd = jobs[j];
        int tt = jd >> 8, idx = jd & 255;
        u64 key = R96[(size_t)tt * MSEL + idx];
        int col = (N_KNOW - 1) - (int)(u32)(key & 0xFFFFFFFFu);
        float p = 0.f;
#pragma unroll
        for (int q = 0; q < 4; ++q) {
            int k = tid + q * 256;
            p = fmaf(x[(size_t)tt * D_MODEL + k], W[(size_t)k * N_KNOW + col], p);
        }
#pragma unroll
        for (int o = 32; o; o >>= 1) p += __shfl_xor(p, o);
        if ((tid & 63) == 0) red[tid >> 6] = p;
        __syncthreads();
        if (tid == 0) {
            float e = red[0] + red[1] + red[2] + red[3];
            nk[(size_t)tt * MSEL + idx] = ((u64)ordf(e) << 32) | (key & 0xFFFFFFFFu);
        }
        __syncthreads();
    }
}

__global__ __launch_bounds__(128)
void k2b_final(const u64* __restrict__ R96, const u64* __restrict__ nk,
               const u32* __restrict__ band, u64* __restrict__ R64)
{
    const int tt = blockIdx.x;
    const int tid = threadIdx.x;
    __shared__ u64 keys[MSEL];
    __shared__ u64 nkk[MSEL];

    const u32 b = band[tt];
    if (tid < MSEL) keys[tid] = R96[(size_t)tt * MSEL + tid];
    const int lo = b & 0xFF, hi = (b >> 8) & 0xFF;
    const bool trivial = (b & 0x80000000u) != 0;
    if (!trivial && tid >= lo && tid <= hi && tid < MSEL)
        nkk[tid] = nk[(size_t)tt * MSEL + tid];
    __syncthreads();

    if (trivial) {
        if (tid < COARSE_K) R64[(size_t)tt * COARSE_K + tid] = keys[tid];
        return;
    }
    if (tid < lo) R64[(size_t)tt * COARSE_K + tid] = keys[tid];
    const int mwin = COARSE_K - lo;
    if (tid >= lo && tid <= hi) {
        u64 me = nkk[tid];
        int r = 0;
        for (int j = lo; j <= hi; ++j) r += (nkk[j] > me) ? 1 : 0;
        if (r < mwin) R64[(size_t)tt * COARSE_K + lo + r] = keys[tid];
    }
}

// ---------------------------------------------------------------------------
// K3f: front-end — one wave per token (4 tokens/block)
// ---------------------------------------------------------------------------
__device__ __forceinline__ void fma4(float4& a, float w, const float4& v) {
    a.x = fmaf(w, v.x, a.x); a.y = fmaf(w, v.y, a.y);
    a.z = fmaf(w, v.z, a.z); a.w = fmaf(w, v.w, a.w);
}

__global__ __launch_bounds__(256)
void k3f(const float* __restrict__ h, const float* __restrict__ Wq,
         const float* __restrict__ Kall, const u64* __restrict__ R,
         int* __restrict__ fidx, float* __restrict__ fw)
{
    __shared__ float hq[4][RANK];
    __shared__ float qv[4][K_RANK_];

    const int tid = threadIdx.x;
    const int w = tid >> 6, lane = tid & 63;
    const int tt = blockIdx.x * 4 + w;

    {
        float2 hv = *(const float2*)(h + (size_t)tt * RANK + lane * 2);
        hq[w][lane * 2] = hv.x;
        hq[w][lane * 2 + 1] = hv.y;
    }
    const u64 key = R[(size_t)tt * COARSE_K + lane];
    const int ci = (N_KNOW - 1) - (int)(u32)(key & 0xFFFFFFFFu);
    __syncthreads();

    {
        float s0 = 0.f, s1 = 0.f;
        const float4* w0 = (const float4*)(Wq + (size_t)(lane * 2) * RANK);
        const float4* w1 = (const float4*)(Wq + (size_t)(lane * 2 + 1) * RANK);
#pragma unroll
        for (int r4 = 0; r4 < RANK / 4; ++r4) {
            float4 a = w0[r4], b = w1[r4];
            const float* hh = &hq[w][r4 * 4];
            s0 = fmaf(a.x, hh[0], s0); s0 = fmaf(a.y, hh[1], s0);
            s0 = fmaf(a.z, hh[2], s0); s0 = fmaf(a.w, hh[3], s0);
            s1 = fmaf(b.x, hh[0], s1); s1 = fmaf(b.y, hh[1], s1);
            s1 = fmaf(b.z, hh[2], s1); s1 = fmaf(b.w, hh[3], s1);
        }
        qv[w][lane * 2] = s0;
        qv[w][lane * 2 + 1] = s1;
    }
    __syncthreads();

    float sc;
    {
        float s = 0.f;
        const float4* kr = (const float4*)(Kall + (size_t)ci * K_RANK_);
#pragma unroll
        for (int r4 = 0; r4 < K_RANK_ / 4; ++r4) {
            float4 a = kr[r4];
            const float* qq = &qv[w][r4 * 4];
            s = fmaf(a.x, qq[0], s); s = fmaf(a.y, qq[1], s);
            s = fmaf(a.z, qq[2], s); s = fmaf(a.w, qq[3], s);
        }
        sc = s * 0.08838834764831845f;   // 1/sqrt(128)
    }

    const u64 myk = ((u64)ordf(sc) << 32) | (u32)(63 - lane);
    int rnk = 0;
#pragma unroll
    for (int j = 0; j < 64; ++j) {
        u64 kj = __shfl(myk, j);
        rnk += (kj > myk) ? 1 : 0;
    }

    float smax = sc;
#pragma unroll
    for (int o = 32; o; o >>= 1) smax = fmaxf(smax, __shfl_xor(smax, o));
    float e = (rnk < FINE_K) ? expf(sc - smax) : 0.f;
    float esum = e;
#pragma unroll
    for (int o = 32; o; o >>= 1) esum += __shfl_xor(esum, o);
    if (rnk < FINE_K) {
        fidx[(size_t)tt * FINE_K + rnk] = ci;
        fw[(size_t)tt * FINE_K + rnk] = e / esum;
    }
}

// ---------------------------------------------------------------------------
// K3g: gather/combine — one token per block
// ---------------------------------------------------------------------------
__global__ __launch_bounds__(256)
void k3g(const int* __restrict__ fidx, const float* __restrict__ fw,
         const float* __restrict__ Vall, float* __restrict__ out)
{
    __shared__ int si[FINE_K];
    __shared__ float sw[FINE_K];
    const int tt = blockIdx.x;
    const int tid = threadIdx.x;
    if (tid < FINE_K) {
        si[tid] = fidx[(size_t)tt * FINE_K + tid];
        sw[tid] = fw[(size_t)tt * FINE_K + tid];
    }
    __syncthreads();

    float4 a = make_float4(0.f, 0.f, 0.f, 0.f);
#pragma unroll
    for (int f = 0; f < FINE_K; ++f) {
        const float4 v = *(const float4*)(Vall + (size_t)si[f] * D_MODEL + tid * 4);
        fma4(a, sw[f], v);
    }
    ((float4*)(out + (size_t)tt * D_MODEL))[tid] = a;
}

// ---------------------------------------------------------------------------
extern "C" void kernel_launch(void* const* d_in, const int* in_sizes, int n_in,
                              void* d_out, int out_size, void* d_ws, size_t ws_size,
                              hipStream_t stream)
{
    const float* x  = (const float*)d_in[0];
    const float* h  = (const float*)d_in[1];
    const float* Wr = (const float*)d_in[2];
    const float* Wq = (const float*)d_in[3];
    const float* Ka = (const float*)d_in[4];
    const float* Va = (const float*)d_in[5];
    float* out = (float*)d_out;

    const size_t fixed =
        (size_t)NTOK * D_MODEL * 2 +      // xh
        (size_t)NTOK * SC * 2 +           // L (u16 fixed-point)
        (size_t)NTOK * MSEL * 8 * 2 +     // R96 + nk
        (size_t)NTOK * COARSE_K * 8 +     // R64
        (size_t)NTOK * MSEL * 4 +         // jobs
        4096 +                            // jobCount (padded)
        (size_t)NTOK * 4 +                // band
        (size_t)NTOK * FINE_K * 8;        // fidx + fw

    int WCH = N_KNOW;
    while (WCH > SC && fixed + (size_t)WCH * D_MODEL * 2 > ws_size)
        WCH >>= 1;

    char* p = (char*)d_ws;
    ushort* wt   = (ushort*)p;  p += (size_t)WCH * D_MODEL * 2;
    ushort* xh   = (ushort*)p;  p += (size_t)NTOK * D_MODEL * 2;
    ushort* Lq   = (ushort*)p;  p += (size_t)NTOK * SC * 2;
    u64*    R96  = (u64*)p;     p += (size_t)NTOK * MSEL * 8;
    u64*    nk   = (u64*)p;     p += (size_t)NTOK * MSEL * 8;
    u64*    R64  = (u64*)p;     p += (size_t)NTOK * COARSE_K * 8;
    u32*    jobs = (u32*)p;     p += (size_t)NTOK * MSEL * 4;
    int*    jobCount = (int*)p; p += 4096;
    u32*    band = (u32*)p;     p += (size_t)NTOK * 4;
    int*    fidx = (int*)p;     p += (size_t)NTOK * FINE_K * 4;
    float*  fw   = (float*)p;   p += (size_t)NTOK * FINE_K * 4;

    hipMemsetAsync(jobCount, 0, 4, stream);

    kcvt_x<<<NTOK * D_MODEL / 4 / 256, 256, 0, stream>>>(x, xh);

    const int nstripe = N_KNOW / SC;                 // 8
    const int spc = WCH / SC;
    for (int s = 0; s < nstripe; ++s) {
        if (s % spc == 0)
            kcvt_wt<<<dim3(WCH / 32, D_MODEL / 32), 256, 0, stream>>>(Wr, wt, s * SC);
        const ushort* wts = wt + (size_t)((s % spc) * SC) * D_MODEL;
        k1f8<<<(SC / 256) * (NTOK / 256), 512, 0, stream>>>(xh, wts, Lq);
        k2_topk<MSEL><<<NTOK, 256, 0, stream>>>(Lq, R96, s * SC, s);
    }

    k2b_band<<<NTOK / 4, 256, 0, stream>>>(R96, jobs, jobCount, band);
    k2b_exec<<<8192, 256, 0, stream>>>(jobs, jobCount, R96, x, Wr, nk);
    k2b_final<<<NTOK, 128, 0, stream>>>(R96, nk, band, R64);

    k3f<<<NTOK / 4, 256, 0, stream>>>(h, Wq, Ka, R64, fidx, fw);
    k3g<<<NTOK, 256, 0, stream>>>(fidx, fw, Va, out);
}

// Round 13
// 689.308 us; speedup vs baseline: 1.2061x; 1.1084x over previous
//
#include <hip/hip_runtime.h>
#include <cstdint>

#define D_MODEL 1024
#define RANK 128
#define K_RANK_ 128
#define N_KNOW 32768
#define COARSE_K 64
#define FINE_K 16
#define NTOK 4096
#define MSEL 96
#define DELTA 1.15e-3f
#define SC 4096
#define QSCALE 8192.0f
#define QINV (1.0f / 8192.0f)

using u32 = unsigned int;
using u64 = unsigned long long;
typedef _Float16 half8 __attribute__((ext_vector_type(8)));
typedef __attribute__((ext_vector_type(4))) float f32x4;

__device__ __forceinline__ u32 ordf(float v) {
    u32 u = __float_as_uint(v);
    return (u & 0x80000000u) ? ~u : (u | 0x80000000u);
}
__device__ __forceinline__ ushort f2h(float f) {
    union { _Float16 h; ushort u; } cv; cv.h = (_Float16)f; return cv.u;
}
__device__ __forceinline__ float h2f(ushort u) {
    union { ushort u; _Float16 h; } cv; cv.u = u; return (float)cv.h;
}
__device__ __forceinline__ void gload16(const void* g, void* l) {
    __builtin_amdgcn_global_load_lds(
        (const __attribute__((address_space(1))) char*)g,
        (__attribute__((address_space(3))) char*)l, 16, 0, 0);
}

// ---------------------------------------------------------------------------
__global__ __launch_bounds__(256)
void kcvt_x(const float* __restrict__ in, ushort* __restrict__ xh)
{
    int i = blockIdx.x * 256 + threadIdx.x;
    float4 v = ((const float4*)in)[i];
    ((ushort4*)xh)[i] = make_ushort4(f2h(v.x), f2h(v.y), f2h(v.z), f2h(v.w));
}

// ---------------------------------------------------------------------------
// Path C: transpose-convert W chunk (hi only) — identical to r12
// ---------------------------------------------------------------------------
__global__ __launch_bounds__(256)
void kcvt_wt(const float* __restrict__ W, ushort* __restrict__ out, int col0)
{
    __shared__ float tile[32][33];
    const int nb = blockIdx.x * 32;
    const int kb = blockIdx.y * 32;
    const int tx = threadIdx.x & 31, ty = threadIdx.x >> 5;
#pragma unroll
    for (int q = 0; q < 4; ++q)
        tile[ty + q * 8][tx] = W[(size_t)(kb + ty + q * 8) * N_KNOW + col0 + nb + tx];
    __syncthreads();
#pragma unroll
    for (int q = 0; q < 4; ++q) {
        float v = tile[tx][ty + q * 8];
        out[(size_t)(nb + ty + q * 8) * D_MODEL + kb + tx] = f2h(v);
    }
}

// ---------------------------------------------------------------------------
// Path A: transpose-convert ALL of W into hi fp16 + lo fp16 (one pass).
// lo = fp16(W - fp16(W)); hi+lo reconstructs W to ~2^-22 rel (Sterbenz).
// ---------------------------------------------------------------------------
__global__ __launch_bounds__(256)
void kcvt_wt2(const float* __restrict__ W, ushort* __restrict__ hi,
              ushort* __restrict__ lo)
{
    __shared__ float tile[32][33];
    const int nb = blockIdx.x * 32;
    const int kb = blockIdx.y * 32;
    const int tx = threadIdx.x & 31, ty = threadIdx.x >> 5;
#pragma unroll
    for (int q = 0; q < 4; ++q)
        tile[ty + q * 8][tx] = W[(size_t)(kb + ty + q * 8) * N_KNOW + nb + tx];
    __syncthreads();
#pragma unroll
    for (int q = 0; q < 4; ++q) {
        float v = tile[tx][ty + q * 8];
        ushort hh = f2h(v);
        ushort ll = f2h(v - h2f(hh));
        size_t o = (size_t)(nb + ty + q * 8) * D_MODEL + kb + tx;
        hi[o] = hh;
        lo[o] = ll;
    }
}

// ---------------------------------------------------------------------------
// K1f8: fp16 MFMA GEMM, 256x256 tile, BK=64, 8-phase counted-vmcnt schedule
// (r9-verified). u16 fixed-point logits out (r12-verified).
// ---------------------------------------------------------------------------
__global__ __launch_bounds__(512, 2)
void k1f8(const ushort* __restrict__ xh, const ushort* __restrict__ wt,
          ushort* __restrict__ L)
{
    __shared__ ushort lds[2][32768];   // [buf][A 256x64 | B 256x64] fp16

    const int tid = threadIdx.x;
    const int nwg = gridDim.x;                       // 256
    int wfl = blockIdx.x;
    wfl = (wfl & 7) * (nwg >> 3) + (wfl >> 3);       // XCD bijective swizzle
    const int bm = (wfl & 15) * 256;
    const int bn = (wfl >> 4) * 256;

    const int lane = tid & 63;
    const int wid = tid >> 6;
    const int wm = wid >> 2, wn = wid & 3;
    const int lr = lane & 15, g = lane >> 4;

    const ushort* gA[4]; const ushort* gB[4];
#pragma unroll
    for (int i = 0; i < 4; ++i) {
        const int o = i * 512 + tid;                 // 0..2047
        const int row = o >> 3;                      // 0..255
        const int gslot = (o & 7) ^ (row & 7);       // involution
        gA[i] = xh + (size_t)(bm + row) * D_MODEL + gslot * 8;
        gB[i] = wt + (size_t)(bn + row) * D_MODEL + gslot * 8;
    }

    int aoff[2][8], boff[2][4];
#pragma unroll
    for (int ks = 0; ks < 2; ++ks) {
#pragma unroll
        for (int mf = 0; mf < 8; ++mf) {
            int row = wm * 128 + mf * 16 + lr;
            aoff[ks][mf] = row * 128 + (((ks * 4 + g) ^ (row & 7)) << 4);
        }
#pragma unroll
        for (int nf = 0; nf < 4; ++nf) {
            int row = wn * 64 + nf * 16 + lr;
            boff[ks][nf] = 32768 + row * 128 + (((ks * 4 + g) ^ (row & 7)) << 4);
        }
    }

    f32x4 acc[8][4];
#pragma unroll
    for (int mf = 0; mf < 8; ++mf)
#pragma unroll
        for (int nf = 0; nf < 4; ++nf) acc[mf][nf] = (f32x4)(0.f);

#define SAH(b, t, h)                                                           \
    {                                                                          \
        gload16(gA[2*(h)]   + (t) * 64,                                        \
                (char*)&lds[(b)][0] + ((2*(h)) * 512 + tid) * 16);             \
        gload16(gA[2*(h)+1] + (t) * 64,                                        \
                (char*)&lds[(b)][0] + ((2*(h)+1) * 512 + tid) * 16);           \
    }
#define SBH(b, t, h)                                                           \
    {                                                                          \
        gload16(gB[2*(h)]   + (t) * 64,                                        \
                (char*)&lds[(b)][0] + 32768 + ((2*(h)) * 512 + tid) * 16);     \
        gload16(gB[2*(h)+1] + (t) * 64,                                        \
                (char*)&lds[(b)][0] + 32768 + ((2*(h)+1) * 512 + tid) * 16);   \
    }

#define LDA4(lb, ks, base)                                                     \
    a0 = *(const half8*)((lb) + aoff[ks][(base) + 0]);                         \
    a1 = *(const half8*)((lb) + aoff[ks][(base) + 1]);                         \
    a2 = *(const half8*)((lb) + aoff[ks][(base) + 2]);                         \
    a3 = *(const half8*)((lb) + aoff[ks][(base) + 3]);

#define LDB4(lb, ks, bb)                                                       \
    bb[0] = *(const half8*)((lb) + boff[ks][0]);                               \
    bb[1] = *(const half8*)((lb) + boff[ks][1]);                               \
    bb[2] = *(const half8*)((lb) + boff[ks][2]);                               \
    bb[3] = *(const half8*)((lb) + boff[ks][3]);

#define MFMA16(mbase, bb)                                                      \
    __builtin_amdgcn_s_setprio(1);                                             \
    _Pragma("unroll")                                                          \
    for (int nf = 0; nf < 4; ++nf) {                                           \
        acc[(mbase)+0][nf] = __builtin_amdgcn_mfma_f32_16x16x32_f16(           \
            a0, bb[nf], acc[(mbase)+0][nf], 0, 0, 0);                          \
        acc[(mbase)+1][nf] = __builtin_amdgcn_mfma_f32_16x16x32_f16(           \
            a1, bb[nf], acc[(mbase)+1][nf], 0, 0, 0);                          \
        acc[(mbase)+2][nf] = __builtin_amdgcn_mfma_f32_16x16x32_f16(           \
            a2, bb[nf], acc[(mbase)+2][nf], 0, 0, 0);                          \
        acc[(mbase)+3][nf] = __builtin_amdgcn_mfma_f32_16x16x32_f16(           \
            a3, bb[nf], acc[(mbase)+3][nf], 0, 0, 0);                          \
    }                                                                          \
    __builtin_amdgcn_s_setprio(0);

#define SBAR()                                                                 \
    __builtin_amdgcn_sched_barrier(0);                                         \
    __builtin_amdgcn_s_barrier();                                              \
    __builtin_amdgcn_sched_barrier(0);

    SBH(0, 0, 0); SBH(0, 0, 1);
    SAH(0, 0, 0); SAH(0, 0, 1);
    SBH(1, 1, 0); SBH(1, 1, 1);

    const char* lb0 = (const char*)&lds[0][0];
    const char* lb1 = (const char*)&lds[1][0];
    half8 b0q[4], b1q[4];

    for (int i = 0; i < 8; ++i) {
        const int t1 = 2 * i + 1;
        const int tn0 = 2 * i + 2, tn1 = 2 * i + 3;
        const bool st = tn0 < 16;
        half8 a0, a1, a2, a3;

        asm volatile("s_waitcnt vmcnt(4)" ::: "memory");
        SBAR();
        LDA4(lb0, 0, 0);
        LDB4(lb0, 0, b0q);
        SAH(1, t1, 0);
        MFMA16(0, b0q);
        LDA4(lb0, 1, 0);
        LDB4(lb0, 1, b1q);
        SAH(1, t1, 1);
        MFMA16(0, b1q);
        SBAR();
        LDA4(lb0, 0, 4);
        if (st) SBH(0, tn0, 0);
        MFMA16(4, b0q);
        LDA4(lb0, 1, 4);
        if (st) SBH(0, tn0, 1);
        MFMA16(4, b1q);
        if (i < 7) asm volatile("s_waitcnt vmcnt(4)" ::: "memory");
        else       asm volatile("s_waitcnt vmcnt(0)" ::: "memory");
        SBAR();
        LDA4(lb1, 0, 0);
        LDB4(lb1, 0, b0q);
        if (st) SAH(0, tn0, 0);
        MFMA16(0, b0q);
        LDA4(lb1, 1, 0);
        LDB4(lb1, 1, b1q);
        if (st) SAH(0, tn0, 1);
        MFMA16(0, b1q);
        SBAR();
        LDA4(lb1, 0, 4);
        if (st) SBH(1, tn1, 0);
        MFMA16(4, b0q);
        LDA4(lb1, 1, 4);
        if (st) SBH(1, tn1, 1);
        MFMA16(4, b1q);
    }
#undef SAH
#undef SBH
#undef LDA4
#undef LDB4
#undef MFMA16
#undef SBAR

    const int crow0 = bm + wm * 128 + g * 4;
    const int ccol  = bn + wn * 64 + lr;
#pragma unroll
    for (int mf = 0; mf < 8; ++mf)
#pragma unroll
        for (int nf = 0; nf < 4; ++nf)
#pragma unroll
            for (int r = 0; r < 4; ++r) {
                int q = __float2int_rn(acc[mf][nf][r] * QSCALE) + 32768;
                q = q < 0 ? 0 : (q > 65535 ? 65535 : q);
                L[(size_t)(crow0 + mf * 16 + r) * SC + ccol + nf * 16] = (ushort)q;
            }
}

// ---------------------------------------------------------------------------
// K2: per-token running top-96 merge per stripe (u16 fixed-point keys).
// ---------------------------------------------------------------------------
template <int M>
__global__ __launch_bounds__(256)
void k2_topk(const ushort* __restrict__ L, u64* __restrict__ R,
             int col0, int stripe)
{
    const int tt = blockIdx.x;
    const int tid = threadIdx.x;

    __shared__ u64 buf[4224];
    __shared__ int scnt;
    __shared__ int sred[4];

    u64 key[16];
    const uint4* row8 = (const uint4*)(L + (size_t)tt * SC);
#pragma unroll
    for (int q = 0; q < 2; ++q) {
        uint4 v = row8[q * 256 + tid];
        const int c = col0 + (q * 256 + tid) * 8;
        u32 wv[4] = {v.x, v.y, v.z, v.w};
#pragma unroll
        for (int d = 0; d < 4; ++d) {
            key[q * 8 + d * 2]     = ((u64)(wv[d] & 0xFFFFu) << 32) | (u32)(N_KNOW - 1 - (c + d * 2));
            key[q * 8 + d * 2 + 1] = ((u64)(wv[d] >> 16) << 32)    | (u32)(N_KNOW - 2 - (c + d * 2));
        }
    }

    u64 tkey;
    if (stripe == 0) {
        u32 lo = 0, hi = 65536;
        for (int it = 0; it < 17; ++it) {
            if (hi - lo <= 1) break;
            u32 mid = lo + ((hi - lo) >> 1);
            int c = 0;
#pragma unroll
            for (int j = 0; j < 16; ++j) c += ((u32)(key[j] >> 32) > mid) ? 1 : 0;
#pragma unroll
            for (int o = 32; o; o >>= 1) c += __shfl_xor(c, o);
            if ((tid & 63) == 0) sred[tid >> 6] = c;
            __syncthreads();
            c = sred[0] + sred[1] + sred[2] + sred[3];
            __syncthreads();
            if (c >= M) { lo = mid; if (c <= 768) break; }
            else hi = mid;
        }
        tkey = ((u64)lo << 32) | 0xFFFFFFFFull;
        if (tid == 0) scnt = 0;
    } else {
        tkey = R[(size_t)tt * M + (M - 1)];
        if (tid < M) buf[tid] = R[(size_t)tt * M + tid];
        if (tid == 0) scnt = M;
    }
    __syncthreads();

#pragma unroll
    for (int j = 0; j < 16; ++j)
        if (key[j] > tkey) {
            int p = atomicAdd(&scnt, 1);
            if (p < 4224) buf[p] = key[j];
        }
    __syncthreads();

    const int n = min(scnt, 4224);
    for (int i = tid; i < n; i += 256) {
        u64 ki = buf[i];
        int r = 0;
        for (int j = 0; j < n; ++j) r += (buf[j] > ki) ? 1 : 0;
        if (r < M) R[(size_t)tt * M + r] = ki;
    }
}

// ---------------------------------------------------------------------------
// K2b pipeline: band -> exec -> final
// ---------------------------------------------------------------------------
__global__ __launch_bounds__(256)
void k2b_band(const u64* __restrict__ R96, u32* __restrict__ jobs,
              int* __restrict__ jobCount, u32* __restrict__ band)
{
    __shared__ float sv[4][MSEL];
    const int tid = threadIdx.x;
    const int w = tid >> 6, lane = tid & 63;
    const int tt = blockIdx.x * 4 + w;

    sv[w][lane] = ((int)(u32)(R96[(size_t)tt * MSEL + lane] >> 32) - 32768) * QINV;
    if (lane < MSEL - 64)
        sv[w][lane + 64] = ((int)(u32)(R96[(size_t)tt * MSEL + lane + 64] >> 32) - 32768) * QINV;
    __syncthreads();

    const float t = sv[w][COARSE_K - 1];
    int cg = 0, cl = 0;
    for (int j = lane; j < MSEL; j += 64) {
        cg += (sv[w][j] > t + DELTA) ? 1 : 0;
        cl += (sv[w][j] < t - DELTA) ? 1 : 0;
    }
#pragma unroll
    for (int o = 32; o; o >>= 1) { cg += __shfl_xor(cg, o); cl += __shfl_xor(cl, o); }

    int lo = cg, hi = MSEL - 1 - cl;
    if (lo > COARSE_K - 1) lo = COARSE_K - 1;
    if (hi < COARSE_K - 1) hi = COARSE_K - 1;

    u32 b;
    if (lo == COARSE_K - 1 && hi == COARSE_K - 1) {
        b = 0x80000000u | 63u | (63u << 8);
    } else {
        int nj = hi - lo + 1;
        int base = 0;
        if (lane == 0) base = atomicAdd(jobCount, nj);
        base = __shfl(base, 0);
        for (int k = lane; k < nj; k += 64)
            jobs[base + k] = ((u32)tt << 8) | (u32)(lo + k);
        b = (u32)lo | ((u32)hi << 8);
    }
    if (lane == 0) band[tt] = b;
}

// Path C: exact f32 re-score via strided W column (r12)
__global__ __launch_bounds__(256)
void k2b_exec(const u32* __restrict__ jobs, const int* __restrict__ jobCount,
              const u64* __restrict__ R96, const float* __restrict__ x,
              const float* __restrict__ W, u64* __restrict__ nk)
{
    __shared__ float red[4];
    const int tid = threadIdx.x;
    const int n = *jobCount;
    for (int j = blockIdx.x; j < n; j += gridDim.x) {
        u32 jd = jobs[j];
        int tt = jd >> 8, idx = jd & 255;
        u64 key = R96[(size_t)tt * MSEL + idx];
        int col = (N_KNOW - 1) - (int)(u32)(key & 0xFFFFFFFFu);
        float p = 0.f;
#pragma unroll
        for (int q = 0; q < 4; ++q) {
            int k = tid + q * 256;
            p = fmaf(x[(size_t)tt * D_MODEL + k], W[(size_t)k * N_KNOW + col], p);
        }
#pragma unroll
        for (int o = 32; o; o >>= 1) p += __shfl_xor(p, o);
        if ((tid & 63) == 0) red[tid >> 6] = p;
        __syncthreads();
        if (tid == 0) {
            float e = red[0] + red[1] + red[2] + red[3];
            nk[(size_t)tt * MSEL + idx] = ((u64)ordf(e) << 32) | (key & 0xFFFFFFFFu);
        }
        __syncthreads();
    }
}

// Path A: exact re-score via contiguous transposed hi+lo fp16 rows.
// score = x_f32 . (hi + lo) where hi+lo == W to ~2^-22 rel.
__global__ __launch_bounds__(256)
void k2b_exec_c(const u32* __restrict__ jobs, const int* __restrict__ jobCount,
                const u64* __restrict__ R96, const float* __restrict__ x,
                const ushort* __restrict__ whi, const ushort* __restrict__ wlo,
                u64* __restrict__ nk)
{
    __shared__ float red[4];
    const int tid = threadIdx.x;
    const int n = *jobCount;
    for (int j = blockIdx.x; j < n; j += gridDim.x) {
        u32 jd = jobs[j];
        int tt = jd >> 8, idx = jd & 255;
        u64 key = R96[(size_t)tt * MSEL + idx];
        int col = (N_KNOW - 1) - (int)(u32)(key & 0xFFFFFFFFu);
        float4 xv = ((const float4*)(x + (size_t)tt * D_MODEL))[tid];
        ushort4 hv = ((const ushort4*)(whi + (size_t)col * D_MODEL))[tid];
        ushort4 lv = ((const ushort4*)(wlo + (size_t)col * D_MODEL))[tid];
        float p = 0.f;
        p = fmaf(xv.x, h2f(hv.x) + h2f(lv.x), p);
        p = fmaf(xv.y, h2f(hv.y) + h2f(lv.y), p);
        p = fmaf(xv.z, h2f(hv.z) + h2f(lv.z), p);
        p = fmaf(xv.w, h2f(hv.w) + h2f(lv.w), p);
#pragma unroll
        for (int o = 32; o; o >>= 1) p += __shfl_xor(p, o);
        if ((tid & 63) == 0) red[tid >> 6] = p;
        __syncthreads();
        if (tid == 0) {
            float e = red[0] + red[1] + red[2] + red[3];
            nk[(size_t)tt * MSEL + idx] = ((u64)ordf(e) << 32) | (key & 0xFFFFFFFFu);
        }
        __syncthreads();
    }
}

__global__ __launch_bounds__(128)
void k2b_final(const u64* __restrict__ R96, const u64* __restrict__ nk,
               const u32* __restrict__ band, u64* __restrict__ R64)
{
    const int tt = blockIdx.x;
    const int tid = threadIdx.x;
    __shared__ u64 keys[MSEL];
    __shared__ u64 nkk[MSEL];

    const u32 b = band[tt];
    if (tid < MSEL) keys[tid] = R96[(size_t)tt * MSEL + tid];
    const int lo = b & 0xFF, hi = (b >> 8) & 0xFF;
    const bool trivial = (b & 0x80000000u) != 0;
    if (!trivial && tid >= lo && tid <= hi && tid < MSEL)
        nkk[tid] = nk[(size_t)tt * MSEL + tid];
    __syncthreads();

    if (trivial) {
        if (tid < COARSE_K) R64[(size_t)tt * COARSE_K + tid] = keys[tid];
        return;
    }
    if (tid < lo) R64[(size_t)tt * COARSE_K + tid] = keys[tid];
    const int mwin = COARSE_K - lo;
    if (tid >= lo && tid <= hi) {
        u64 me = nkk[tid];
        int r = 0;
        for (int j = lo; j <= hi; ++j) r += (nkk[j] > me) ? 1 : 0;
        if (r < mwin) R64[(size_t)tt * COARSE_K + lo + r] = keys[tid];
    }
}

// ---------------------------------------------------------------------------
// K3f: front-end — one wave per token (4 tokens/block)
// ---------------------------------------------------------------------------
__device__ __forceinline__ void fma4(float4& a, float w, const float4& v) {
    a.x = fmaf(w, v.x, a.x); a.y = fmaf(w, v.y, a.y);
    a.z = fmaf(w, v.z, a.z); a.w = fmaf(w, v.w, a.w);
}

__global__ __launch_bounds__(256)
void k3f(const float* __restrict__ h, const float* __restrict__ Wq,
         const float* __restrict__ Kall, const u64* __restrict__ R,
         int* __restrict__ fidx, float* __restrict__ fw)
{
    __shared__ float hq[4][RANK];
    __shared__ float qv[4][K_RANK_];

    const int tid = threadIdx.x;
    const int w = tid >> 6, lane = tid & 63;
    const int tt = blockIdx.x * 4 + w;

    {
        float2 hv = *(const float2*)(h + (size_t)tt * RANK + lane * 2);
        hq[w][lane * 2] = hv.x;
        hq[w][lane * 2 + 1] = hv.y;
    }
    const u64 key = R[(size_t)tt * COARSE_K + lane];
    const int ci = (N_KNOW - 1) - (int)(u32)(key & 0xFFFFFFFFu);
    __syncthreads();

    {
        float s0 = 0.f, s1 = 0.f;
        const float4* w0 = (const float4*)(Wq + (size_t)(lane * 2) * RANK);
        const float4* w1 = (const float4*)(Wq + (size_t)(lane * 2 + 1) * RANK);
#pragma unroll
        for (int r4 = 0; r4 < RANK / 4; ++r4) {
            float4 a = w0[r4], b = w1[r4];
            const float* hh = &hq[w][r4 * 4];
            s0 = fmaf(a.x, hh[0], s0); s0 = fmaf(a.y, hh[1], s0);
            s0 = fmaf(a.z, hh[2], s0); s0 = fmaf(a.w, hh[3], s0);
            s1 = fmaf(b.x, hh[0], s1); s1 = fmaf(b.y, hh[1], s1);
            s1 = fmaf(b.z, hh[2], s1); s1 = fmaf(b.w, hh[3], s1);
        }
        qv[w][lane * 2] = s0;
        qv[w][lane * 2 + 1] = s1;
    }
    __syncthreads();

    float sc;
    {
        float s = 0.f;
        const float4* kr = (const float4*)(Kall + (size_t)ci * K_RANK_);
#pragma unroll
        for (int r4 = 0; r4 < K_RANK_ / 4; ++r4) {
            float4 a = kr[r4];
            const float* qq = &qv[w][r4 * 4];
            s = fmaf(a.x, qq[0], s); s = fmaf(a.y, qq[1], s);
            s = fmaf(a.z, qq[2], s); s = fmaf(a.w, qq[3], s);
        }
        sc = s * 0.08838834764831845f;   // 1/sqrt(128)
    }

    const u64 myk = ((u64)ordf(sc) << 32) | (u32)(63 - lane);
    int rnk = 0;
#pragma unroll
    for (int j = 0; j < 64; ++j) {
        u64 kj = __shfl(myk, j);
        rnk += (kj > myk) ? 1 : 0;
    }

    float smax = sc;
#pragma unroll
    for (int o = 32; o; o >>= 1) smax = fmaxf(smax, __shfl_xor(smax, o));
    float e = (rnk < FINE_K) ? expf(sc - smax) : 0.f;
    float esum = e;
#pragma unroll
    for (int o = 32; o; o >>= 1) esum += __shfl_xor(esum, o);
    if (rnk < FINE_K) {
        fidx[(size_t)tt * FINE_K + rnk] = ci;
        fw[(size_t)tt * FINE_K + rnk] = e / esum;
    }
}

// ---------------------------------------------------------------------------
// K3g: gather/combine — one token per block
// ---------------------------------------------------------------------------
__global__ __launch_bounds__(256)
void k3g(const int* __restrict__ fidx, const float* __restrict__ fw,
         const float* __restrict__ Vall, float* __restrict__ out)
{
    __shared__ int si[FINE_K];
    __shared__ float sw[FINE_K];
    const int tt = blockIdx.x;
    const int tid = threadIdx.x;
    if (tid < FINE_K) {
        si[tid] = fidx[(size_t)tt * FINE_K + tid];
        sw[tid] = fw[(size_t)tt * FINE_K + tid];
    }
    __syncthreads();

    float4 a = make_float4(0.f, 0.f, 0.f, 0.f);
#pragma unroll
    for (int f = 0; f < FINE_K; ++f) {
        const float4 v = *(const float4*)(Vall + (size_t)si[f] * D_MODEL + tid * 4);
        fma4(a, sw[f], v);
    }
    ((float4*)(out + (size_t)tt * D_MODEL))[tid] = a;
}

// ---------------------------------------------------------------------------
extern "C" void kernel_launch(void* const* d_in, const int* in_sizes, int n_in,
                              void* d_out, int out_size, void* d_ws, size_t ws_size,
                              hipStream_t stream)
{
    const float* x  = (const float*)d_in[0];
    const float* h  = (const float*)d_in[1];
    const float* Wr = (const float*)d_in[2];
    const float* Wq = (const float*)d_in[3];
    const float* Ka = (const float*)d_in[4];
    const float* Va = (const float*)d_in[5];
    float* out = (float*)d_out;

    const size_t fixed =
        (size_t)NTOK * D_MODEL * 2 +      // xh
        (size_t)NTOK * SC * 2 +           // Lq (u16 fixed-point)
        (size_t)NTOK * MSEL * 8 * 2 +     // R96 + nk
        (size_t)NTOK * COARSE_K * 8 +     // R64
        (size_t)NTOK * MSEL * 4 +         // jobs
        4096 +                            // jobCount (padded)
        (size_t)NTOK * 4 +                // band
        (size_t)NTOK * FINE_K * 8;        // fidx + fw

    const size_t WFULL = (size_t)N_KNOW * D_MODEL * 2;   // 64 MB
    const bool pathA = fixed + 2 * WFULL <= ws_size;     // hi + lo full

    char* p = (char*)d_ws;
    ushort* wt   = (ushort*)p;
    ushort* wlo  = nullptr;
    int WCH;
    if (pathA) {
        WCH = N_KNOW;
        p += WFULL;
        wlo = (ushort*)p; p += WFULL;
    } else {
        WCH = N_KNOW;
        while (WCH > SC && fixed + (size_t)WCH * D_MODEL * 2 > ws_size)
            WCH >>= 1;
        p += (size_t)WCH * D_MODEL * 2;
    }
    ushort* xh   = (ushort*)p;  p += (size_t)NTOK * D_MODEL * 2;
    ushort* Lq   = (ushort*)p;  p += (size_t)NTOK * SC * 2;
    u64*    R96  = (u64*)p;     p += (size_t)NTOK * MSEL * 8;
    u64*    nk   = (u64*)p;     p += (size_t)NTOK * MSEL * 8;
    u64*    R64  = (u64*)p;     p += (size_t)NTOK * COARSE_K * 8;
    u32*    jobs = (u32*)p;     p += (size_t)NTOK * MSEL * 4;
    int*    jobCount = (int*)p; p += 4096;
    u32*    band = (u32*)p;     p += (size_t)NTOK * 4;
    int*    fidx = (int*)p;     p += (size_t)NTOK * FINE_K * 4;
    float*  fw   = (float*)p;   p += (size_t)NTOK * FINE_K * 4;

    hipMemsetAsync(jobCount, 0, 4, stream);

    kcvt_x<<<NTOK * D_MODEL / 4 / 256, 256, 0, stream>>>(x, xh);

    const int nstripe = N_KNOW / SC;                 // 8
    if (pathA) {
        kcvt_wt2<<<dim3(N_KNOW / 32, D_MODEL / 32), 256, 0, stream>>>(Wr, wt, wlo);
        for (int s = 0; s < nstripe; ++s) {
            const ushort* wts = wt + (size_t)(s * SC) * D_MODEL;
            k1f8<<<(SC / 256) * (NTOK / 256), 512, 0, stream>>>(xh, wts, Lq);
            k2_topk<MSEL><<<NTOK, 256, 0, stream>>>(Lq, R96, s * SC, s);
        }
    } else {
        const int spc = WCH / SC;
        for (int s = 0; s < nstripe; ++s) {
            if (s % spc == 0)
                kcvt_wt<<<dim3(WCH / 32, D_MODEL / 32), 256, 0, stream>>>(Wr, wt, s * SC);
            const ushort* wts = wt + (size_t)((s % spc) * SC) * D_MODEL;
            k1f8<<<(SC / 256) * (NTOK / 256), 512, 0, stream>>>(xh, wts, Lq);
            k2_topk<MSEL><<<NTOK, 256, 0, stream>>>(Lq, R96, s * SC, s);
        }
    }

    k2b_band<<<NTOK / 4, 256, 0, stream>>>(R96, jobs, jobCount, band);
    if (pathA)
        k2b_exec_c<<<8192, 256, 0, stream>>>(jobs, jobCount, R96, x, wt, wlo, nk);
    else
        k2b_exec<<<8192, 256, 0, stream>>>(jobs, jobCount, R96, x, Wr, nk);
    k2b_final<<<NTOK, 128, 0, stream>>>(R96, nk, band, R64);

    k3f<<<NTOK / 4, 256, 0, stream>>>(h, Wq, Ka, R64, fidx, fw);
    k3g<<<NTOK, 256, 0, stream>>>(fidx, fw, Va, out);
}